// Round 11
// baseline (145.807 us; speedup 1.0000x reference)
//
#include <hip/hip_runtime.h>
#include <hip/hip_cooperative_groups.h>

#define M_ 256
#define K_ 8192
#define N_ 8192

typedef int v4i __attribute__((ext_vector_type(4)));
typedef int v16i __attribute__((ext_vector_type(16)));

namespace cg = cooperative_groups;

// xq tiled layout (bijective byte map, 2 MB):
//   (m,k) -> addr = (mt<<18) + (chunk<<13) + (ks<<10) + (lane<<4) + b
//   mt=m>>5, chunk=k>>8, ks=(k>>5)&7, lane=(m&31)+32*((k>>4)&1), b=k&15

// byte-transpose: 4 k-rows (w0..w3), cols j=0..3 -> dword per col at +j*272
__device__ __forceinline__ void stage_b(char* btn, int bwo,
                                        const int4& w0, const int4& w1,
                                        const int4& w2, const int4& w3) {
    const int* p0 = (const int*)&w0;
    const int* p1 = (const int*)&w1;
    const int* p2 = (const int*)&w2;
    const int* p3 = (const int*)&w3;
#pragma unroll
    for (int j = 0; j < 4; ++j) {
        const unsigned u = __builtin_amdgcn_perm((unsigned)p1[j], (unsigned)p0[j], 0x00000400u);
        const unsigned w = __builtin_amdgcn_perm((unsigned)p3[j], (unsigned)p2[j], 0x00000400u);
        const unsigned o = __builtin_amdgcn_perm(w, u, 0x05040100u);
        *(unsigned*)(btn + bwo + j * 272) = o;
    }
}

// ---------------- fused cooperative kernel: quant -> grid.sync -> gemm -----
// grid 256 x 512 (1 block/CU). Part 1: block b quantizes token row m=b.
// Part 2: R6 gemm body (best structure, 63.9us): 32 phases, A-refill (L2)
// before qw loadq (HBM), aE/aO ping-pong, one raw barrier per phase,
// lgkmcnt-only drain, never vmcnt(0).
__global__ __launch_bounds__(512) void awq_fused(const float* __restrict__ x,
                                                 signed char* __restrict__ xqt,
                                                 float* __restrict__ scales,
                                                 const int* __restrict__ qw,
                                                 const float* __restrict__ wscale,
                                                 const float* __restrict__ bias,
                                                 float* __restrict__ out) {
    __shared__ __align__(16) char btile[2][32 * 272];
    __shared__ float red[8];
    const int t = threadIdx.x;
    const int bid = blockIdx.x;

    // ---------------- part 1: quantize row m = bid ----------------
    {
        const int m = bid;
        const float4* xrow = (const float4*)(x + (size_t)m * K_);
        float4 v[4];
        float mx = 0.0f;
#pragma unroll
        for (int j = 0; j < 4; ++j) {
            v[j] = xrow[j * 512 + t];
            mx = fmaxf(mx, fmaxf(fmaxf(fabsf(v[j].x), fabsf(v[j].y)),
                                 fmaxf(fabsf(v[j].z), fabsf(v[j].w))));
        }
#pragma unroll
        for (int off = 32; off > 0; off >>= 1) mx = fmaxf(mx, __shfl_xor(mx, off, 64));
        if ((t & 63) == 0) red[t >> 6] = mx;
        __syncthreads();
        mx = fmaxf(fmaxf(fmaxf(red[0], red[1]), fmaxf(red[2], red[3])),
                   fmaxf(fmaxf(red[4], red[5]), fmaxf(red[6], red[7])));
        const float scale = fmaxf(mx / 127.0f, 1e-8f);

        char* base = (char*)xqt + ((size_t)(m >> 5) << 18);
        const int ml = m & 31;
#pragma unroll
        for (int j = 0; j < 4; ++j) {
            const int q0 = (int)fminf(fmaxf(rintf(v[j].x / scale), -127.0f), 127.0f);
            const int q1 = (int)fminf(fmaxf(rintf(v[j].y / scale), -127.0f), 127.0f);
            const int q2 = (int)fminf(fmaxf(rintf(v[j].z / scale), -127.0f), 127.0f);
            const int q3 = (int)fminf(fmaxf(rintf(v[j].w / scale), -127.0f), 127.0f);
            const int packed = (q0 & 255) | ((q1 & 255) << 8) | ((q2 & 255) << 16) | ((q3 & 255) << 24);
            const int k0 = 4 * (j * 512 + t);
            const int addr = ((k0 >> 8) << 13) + (((k0 >> 5) & 7) << 10) +
                             ((ml + (((k0 >> 4) & 1) << 5)) << 4) + (k0 & 15);
            *(int*)(base + addr) = packed;
        }
        if (t == 0) scales[m] = scale;
    }

    __threadfence();
    cg::this_grid().sync();

    // ---------------- part 2: gemm (R6 body) ----------------
    const int lane = t & 63;
    const int wave = t >> 6;
    const int n0 = bid * 32;

    const int sa = t & 7;                  // n-group
    const int sr = t >> 3;                 // k-row group (0..63)
    const int* qbase = qw + (size_t)(4 * sr) * N_ + n0 + 4 * sa;

    const signed char* xqb = xqt + ((size_t)wave << 18) + lane * 16;

    const int bro = (lane & 31) * 272 + (lane >> 5) * 16;
    const int bwo = (4 * sa) * 272 + 4 * sr;

    v16i acc = {};
    v4i aE[8], aO[8];
    int4 sA[4], sB[4];

    auto loadq = [&](int4* dst, int chunk) {
        const int4* q = (const int4*)(qbase + (size_t)chunk * 256 * N_);
        dst[0] = q[0];
        dst[1] = q[N_ / 4];
        dst[2] = q[2 * (N_ / 4)];
        dst[3] = q[3 * (N_ / 4)];
    };

#pragma unroll
    for (int ks = 0; ks < 8; ++ks) aE[ks] = *(const v4i*)(xqb + ks * 1024);
    loadq(sA, 0);
    loadq(sB, 1);
    stage_b(&btile[0][0], bwo, sA[0], sA[1], sA[2], sA[3]);
    asm volatile("s_waitcnt lgkmcnt(0)" ::: "memory");
    __builtin_amdgcn_s_barrier();
    __builtin_amdgcn_sched_barrier(0);

    for (int sc = 0; sc < 32; sc += 2) {
        {   // even: compute chunk sc (buf0, aE); refill aO<-sc+1; loadq sA<-sc+2
            const int ra = (sc + 1 < 32) ? sc + 1 : 31;
#pragma unroll
            for (int ks = 0; ks < 8; ++ks)
                aO[ks] = *(const v4i*)(xqb + ra * 8192 + ks * 1024);
            loadq(sA, (sc + 2 < 32) ? sc + 2 : 31);
            __builtin_amdgcn_sched_barrier(0);
            const char* btc = &btile[0][0];
#pragma unroll
            for (int ks = 0; ks < 8; ++ks) {
                const v4i bf = *(const v4i*)(btc + bro + ks * 32);
                acc = __builtin_amdgcn_mfma_i32_32x32x32_i8(aE[ks], bf, acc, 0, 0, 0);
            }
            stage_b(&btile[1][0], bwo, sB[0], sB[1], sB[2], sB[3]);
            asm volatile("s_waitcnt lgkmcnt(0)" ::: "memory");
            __builtin_amdgcn_s_barrier();
            __builtin_amdgcn_sched_barrier(0);
        }
        {   // odd: compute chunk sc+1 (buf1, aO); refill aE<-sc+2; loadq sB<-sc+3
            const int ra = (sc + 2 < 32) ? sc + 2 : 31;
#pragma unroll
            for (int ks = 0; ks < 8; ++ks)
                aE[ks] = *(const v4i*)(xqb + ra * 8192 + ks * 1024);
            loadq(sB, (sc + 3 < 32) ? sc + 3 : 31);
            __builtin_amdgcn_sched_barrier(0);
            const char* btc = &btile[1][0];
#pragma unroll
            for (int ks = 0; ks < 8; ++ks) {
                const v4i bf = *(const v4i*)(btc + bro + ks * 32);
                acc = __builtin_amdgcn_mfma_i32_32x32x32_i8(aO[ks], bf, acc, 0, 0, 0);
            }
            stage_b(&btile[0][0], bwo, sA[0], sA[1], sA[2], sA[3]);
            asm volatile("s_waitcnt lgkmcnt(0)" ::: "memory");
            __builtin_amdgcn_s_barrier();
            __builtin_amdgcn_sched_barrier(0);
        }
    }

    // epilogue: dequant. C/D layout: col=lane&31, row=(g&3)+8*(g>>2)+4*(lane>>5)
    const int n = n0 + (lane & 31);
    const float wn = wscale[n];
    const float bn = bias[n];
    const int mb = wave * 32 + 4 * (lane >> 5);
#pragma unroll
    for (int g = 0; g < 16; ++g) {
        const int m = mb + (g & 3) + 8 * (g >> 2);
        out[(size_t)m * N_ + n] = ((float)acc[g] * scales[m]) * wn + bn;
    }
}

// ---------------- fallback kernels (two-launch path, R6) ----------------
__global__ __launch_bounds__(256) void awq_quant(const float* __restrict__ x,
                                                 signed char* __restrict__ xqt,
                                                 float* __restrict__ scales) {
    const int m = blockIdx.x;
    const int t = threadIdx.x;
    const float4* xrow = (const float4*)(x + (size_t)m * K_);
    float4 v[8];
    float mx = 0.0f;
#pragma unroll
    for (int j = 0; j < 8; ++j) {
        v[j] = xrow[j * 256 + t];
        mx = fmaxf(mx, fmaxf(fmaxf(fabsf(v[j].x), fabsf(v[j].y)),
                             fmaxf(fabsf(v[j].z), fabsf(v[j].w))));
    }
#pragma unroll
    for (int off = 32; off > 0; off >>= 1) mx = fmaxf(mx, __shfl_xor(mx, off, 64));
    __shared__ float red[4];
    if ((t & 63) == 0) red[t >> 6] = mx;
    __syncthreads();
    mx = fmaxf(fmaxf(red[0], red[1]), fmaxf(red[2], red[3]));
    const float scale = fmaxf(mx / 127.0f, 1e-8f);

    char* base = (char*)xqt + ((size_t)(m >> 5) << 18);
    const int ml = m & 31;
#pragma unroll
    for (int j = 0; j < 8; ++j) {
        const int q0 = (int)fminf(fmaxf(rintf(v[j].x / scale), -127.0f), 127.0f);
        const int q1 = (int)fminf(fmaxf(rintf(v[j].y / scale), -127.0f), 127.0f);
        const int q2 = (int)fminf(fmaxf(rintf(v[j].z / scale), -127.0f), 127.0f);
        const int q3 = (int)fminf(fmaxf(rintf(v[j].w / scale), -127.0f), 127.0f);
        const int packed = (q0 & 255) | ((q1 & 255) << 8) | ((q2 & 255) << 16) | ((q3 & 255) << 24);
        const int k0 = 4 * (j * 256 + t);
        const int addr = ((k0 >> 8) << 13) + (((k0 >> 5) & 7) << 10) +
                         ((ml + (((k0 >> 4) & 1) << 5)) << 4) + (k0 & 15);
        *(int*)(base + addr) = packed;
    }
    if (t == 0) scales[m] = scale;
}

__global__ __launch_bounds__(512) void awq_gemm(const signed char* __restrict__ xqt,
                                                const float* __restrict__ scales,
                                                const int* __restrict__ qw,
                                                const float* __restrict__ wscale,
                                                const float* __restrict__ bias,
                                                float* __restrict__ out) {
    __shared__ __align__(16) char btile[2][32 * 272];
    const int t = threadIdx.x;
    const int lane = t & 63;
    const int wave = t >> 6;
    const int n0 = blockIdx.x * 32;
    const int sa = t & 7;
    const int sr = t >> 3;
    const int* qbase = qw + (size_t)(4 * sr) * N_ + n0 + 4 * sa;
    const signed char* xqb = xqt + ((size_t)wave << 18) + lane * 16;
    const int bro = (lane & 31) * 272 + (lane >> 5) * 16;
    const int bwo = (4 * sa) * 272 + 4 * sr;

    v16i acc = {};
    v4i aE[8], aO[8];
    int4 sA[4], sB[4];
    auto loadq = [&](int4* dst, int chunk) {
        const int4* q = (const int4*)(qbase + (size_t)chunk * 256 * N_);
        dst[0] = q[0]; dst[1] = q[N_ / 4]; dst[2] = q[2 * (N_ / 4)]; dst[3] = q[3 * (N_ / 4)];
    };
#pragma unroll
    for (int ks = 0; ks < 8; ++ks) aE[ks] = *(const v4i*)(xqb + ks * 1024);
    loadq(sA, 0);
    loadq(sB, 1);
    stage_b(&btile[0][0], bwo, sA[0], sA[1], sA[2], sA[3]);
    asm volatile("s_waitcnt lgkmcnt(0)" ::: "memory");
    __builtin_amdgcn_s_barrier();
    __builtin_amdgcn_sched_barrier(0);

    for (int sc = 0; sc < 32; sc += 2) {
        {
            const int ra = (sc + 1 < 32) ? sc + 1 : 31;
#pragma unroll
            for (int ks = 0; ks < 8; ++ks)
                aO[ks] = *(const v4i*)(xqb + ra * 8192 + ks * 1024);
            loadq(sA, (sc + 2 < 32) ? sc + 2 : 31);
            __builtin_amdgcn_sched_barrier(0);
            const char* btc = &btile[0][0];
#pragma unroll
            for (int ks = 0; ks < 8; ++ks) {
                const v4i bf = *(const v4i*)(btc + bro + ks * 32);
                acc = __builtin_amdgcn_mfma_i32_32x32x32_i8(aE[ks], bf, acc, 0, 0, 0);
            }
            stage_b(&btile[1][0], bwo, sB[0], sB[1], sB[2], sB[3]);
            asm volatile("s_waitcnt lgkmcnt(0)" ::: "memory");
            __builtin_amdgcn_s_barrier();
            __builtin_amdgcn_sched_barrier(0);
        }
        {
            const int ra = (sc + 2 < 32) ? sc + 2 : 31;
#pragma unroll
            for (int ks = 0; ks < 8; ++ks)
                aE[ks] = *(const v4i*)(xqb + ra * 8192 + ks * 1024);
            loadq(sB, (sc + 3 < 32) ? sc + 3 : 31);
            __builtin_amdgcn_sched_barrier(0);
            const char* btc = &btile[1][0];
#pragma unroll
            for (int ks = 0; ks < 8; ++ks) {
                const v4i bf = *(const v4i*)(btc + bro + ks * 32);
                acc = __builtin_amdgcn_mfma_i32_32x32x32_i8(aO[ks], bf, acc, 0, 0, 0);
            }
            stage_b(&btile[0][0], bwo, sA[0], sA[1], sA[2], sA[3]);
            asm volatile("s_waitcnt lgkmcnt(0)" ::: "memory");
            __builtin_amdgcn_s_barrier();
            __builtin_amdgcn_sched_barrier(0);
        }
    }
    const int n = n0 + (lane & 31);
    const float wn = wscale[n];
    const float bn = bias[n];
    const int mb = wave * 32 + 4 * (lane >> 5);
#pragma unroll
    for (int g = 0; g < 16; ++g) {
        const int m = mb + (g & 3) + 8 * (g >> 2);
        out[(size_t)m * N_ + n] = ((float)acc[g] * scales[m]) * wn + bn;
    }
}

extern "C" void kernel_launch(void* const* d_in, const int* in_sizes, int n_in,
                              void* d_out, int out_size, void* d_ws, size_t ws_size,
                              hipStream_t stream) {
    const float* x    = (const float*)d_in[0];
    const int*   qw   = (const int*)d_in[1];
    const float* wsc  = (const float*)d_in[2];
    const float* bias = (const float*)d_in[3];
    float* out = (float*)d_out;

    signed char* xqbuf  = (signed char*)d_ws;                      // 2 MB, tiled
    float*       scales = (float*)((char*)d_ws + (size_t)M_ * K_); // 1 KB

    void* args[] = {(void*)&x, (void*)&xqbuf, (void*)&scales, (void*)&qw,
                    (void*)&wsc, (void*)&bias, (void*)&out};
    hipError_t err = hipLaunchCooperativeKernel((const void*)awq_fused,
                                                dim3(256), dim3(512),
                                                args, 0, stream);
    if (err != hipSuccess) {
        awq_quant<<<M_, 256, 0, stream>>>(x, xqbuf, scales);
        awq_gemm<<<N_ / 32, 512, 0, stream>>>(xqbuf, scales, qw, wsc, bias, out);
    }
}

// Round 13
// 68.737 us; speedup vs baseline: 2.1212x; 2.1212x over previous
//
#include <hip/hip_runtime.h>

#define M_ 256
#define K_ 8192
#define N_ 8192

typedef int v4i __attribute__((ext_vector_type(4)));
typedef int v16i __attribute__((ext_vector_type(16)));

// ---------------- kernel 1: per-token int8 quantization (R6, proven) ------
// xq tiled layout (bijective byte map, 2 MB):
//   (m,k) -> addr = (mt<<18) + (chunk<<13) + (ks<<10) + (lane<<4) + b
__global__ __launch_bounds__(256) void awq_quant(const float* __restrict__ x,
                                                 signed char* __restrict__ xqt,
                                                 float* __restrict__ scales) {
    const int m = blockIdx.x;
    const int t = threadIdx.x;
    const float4* xrow = (const float4*)(x + (size_t)m * K_);
    float4 v[8];
    float mx = 0.0f;
#pragma unroll
    for (int j = 0; j < 8; ++j) {
        v[j] = xrow[j * 256 + t];
        mx = fmaxf(mx, fmaxf(fmaxf(fabsf(v[j].x), fabsf(v[j].y)),
                             fmaxf(fabsf(v[j].z), fabsf(v[j].w))));
    }
#pragma unroll
    for (int off = 32; off > 0; off >>= 1) mx = fmaxf(mx, __shfl_xor(mx, off, 64));
    __shared__ float red[4];
    if ((t & 63) == 0) red[t >> 6] = mx;
    __syncthreads();
    mx = fmaxf(fmaxf(red[0], red[1]), fmaxf(red[2], red[3]));
    const float scale = fmaxf(mx / 127.0f, 1e-8f);

    char* base = (char*)xqt + ((size_t)(m >> 5) << 18);
    const int ml = m & 31;
#pragma unroll
    for (int j = 0; j < 8; ++j) {
        const int q0 = (int)fminf(fmaxf(rintf(v[j].x / scale), -127.0f), 127.0f);
        const int q1 = (int)fminf(fmaxf(rintf(v[j].y / scale), -127.0f), 127.0f);
        const int q2 = (int)fminf(fmaxf(rintf(v[j].z / scale), -127.0f), 127.0f);
        const int q3 = (int)fminf(fmaxf(rintf(v[j].w / scale), -127.0f), 127.0f);
        const int packed = (q0 & 255) | ((q1 & 255) << 8) | ((q2 & 255) << 16) | ((q3 & 255) << 24);
        const int k0 = 4 * (j * 256 + t);
        const int addr = ((k0 >> 8) << 13) + (((k0 >> 5) & 7) << 10) +
                         ((ml + (((k0 >> 4) & 1) << 5)) << 4) + (k0 & 15);
        *(int*)(base + addr) = packed;
    }
    if (t == 0) scales[m] = scale;
}

// ---------------- kernel 2: producer-consumer int8 GEMM -------------------
// grid = 256 (1 block/CU), 512 thr = 8 waves. NO barriers in steady state.
// Waves 4-7 = producers: producer p owns LDS buffer p and chunks c%4==p.
// Waves 0-3 = consumers: wave w owns m-tiles 2w,2w+1.
// Signaling: wave-wide asm lgkmcnt(0) (covers ALL lanes' ds ops: lgkmcnt is
// a wave-level counter) THEN lane0-only atomic (R12 bug: per-lane atomics
// inflated done[] 64x -> producer overwrote live buffers).
__global__ __launch_bounds__(512) void awq_gemm_pc(const signed char* __restrict__ xqt,
                                                   const float* __restrict__ scales,
                                                   const int* __restrict__ qw,
                                                   const float* __restrict__ wscale,
                                                   const float* __restrict__ bias,
                                                   float* __restrict__ out) {
    __shared__ __align__(16) char bufs[4][32 * 272];   // 34816 B
    __shared__ int fill[4];
    __shared__ int done[4];
    const int t = threadIdx.x;
    const int lane = t & 63;
    const int wave = t >> 6;
    const int n0 = blockIdx.x * 32;

    if (t < 4) { fill[t] = 0; done[t] = 0; }
    __syncthreads();

    if (wave >= 4) {
        // ---------------- producer wave p ----------------
        const int p = wave - 4;
        const int jg = lane & 7;          // col group: cols n0 + 4jg + j
        const int q  = lane >> 3;         // base row-quad 0..7
        const int* qb = qw + (size_t)(4 * q) * N_ + n0 + 4 * jg;
        char* bp = &bufs[p][0];

        for (int c = p; c < 32; c += 4) {
            if (c >= 4) {
                const int need = (c >> 2) * 4;   // 4 consumer waves per prior chunk
                while (__atomic_load_n(&done[p], __ATOMIC_ACQUIRE) < need)
                    __builtin_amdgcn_s_sleep(2);
            }
            __builtin_amdgcn_sched_barrier(0);
            const int* qc = qb + (size_t)c * 256 * N_;
            int4 w[32];
#pragma unroll
            for (int i = 0; i < 8; ++i)
#pragma unroll
                for (int r = 0; r < 4; ++r)
                    w[i * 4 + r] = *(const int4*)(qc + (size_t)(32 * i + r) * N_);
#pragma unroll
            for (int i = 0; i < 8; ++i) {
                const int* p0 = (const int*)&w[i * 4 + 0];
                const int* p1 = (const int*)&w[i * 4 + 1];
                const int* p2 = (const int*)&w[i * 4 + 2];
                const int* p3 = (const int*)&w[i * 4 + 3];
#pragma unroll
                for (int j = 0; j < 4; ++j) {
                    const unsigned u = __builtin_amdgcn_perm((unsigned)p1[j], (unsigned)p0[j], 0x00000400u);
                    const unsigned v = __builtin_amdgcn_perm((unsigned)p3[j], (unsigned)p2[j], 0x00000400u);
                    const unsigned o = __builtin_amdgcn_perm(v, u, 0x05040100u);
                    *(unsigned*)(bp + (4 * jg + j) * 272 + 4 * (q + 8 * i)) = o;
                }
            }
            asm volatile("s_waitcnt lgkmcnt(0)" ::: "memory");  // wave-wide ds_write drain
            __builtin_amdgcn_sched_barrier(0);
            if (lane == 0)
                __atomic_store_n(&fill[p], c + 1, __ATOMIC_RELEASE);
        }
    } else {
        // ---------------- consumer wave w ----------------
        const signed char* xqb0 = xqt + ((size_t)(2 * wave) << 18) + lane * 16;
        const signed char* xqb1 = xqb0 + (1 << 18);
        const int bro = (lane & 31) * 272 + (lane >> 5) * 16;
        v16i acc0 = {}, acc1 = {};
        v4i aE[16], aO[16];

        // preload aE <- chunk 0
#pragma unroll
        for (int f = 0; f < 8; ++f) {
            aE[f]     = *(const v4i*)(xqb0 + f * 1024);
            aE[f + 8] = *(const v4i*)(xqb1 + f * 1024);
        }

#define CONSUME(C_, ACUR, ANXT)                                                          \
    {                                                                                    \
        const int ra = ((C_) + 1 < 32) ? (C_) + 1 : 31;                                  \
        _Pragma("unroll")                                                                \
        for (int f = 0; f < 8; ++f) {                                                    \
            ANXT[f]     = *(const v4i*)(xqb0 + (size_t)ra * 8192 + f * 1024);            \
            ANXT[f + 8] = *(const v4i*)(xqb1 + (size_t)ra * 8192 + f * 1024);            \
        }                                                                                \
        const int b = (C_) & 3;                                                          \
        while (__atomic_load_n(&fill[b], __ATOMIC_ACQUIRE) < (C_) + 1)                   \
            __builtin_amdgcn_s_sleep(2);                                                 \
        __builtin_amdgcn_sched_barrier(0);                                               \
        const char* btc = &bufs[b][0];                                                   \
        _Pragma("unroll")                                                                \
        for (int f = 0; f < 8; ++f) {                                                    \
            const v4i bf = *(const v4i*)(btc + bro + f * 32);                            \
            acc0 = __builtin_amdgcn_mfma_i32_32x32x32_i8(ACUR[f], bf, acc0, 0, 0, 0);    \
            acc1 = __builtin_amdgcn_mfma_i32_32x32x32_i8(ACUR[f + 8], bf, acc1, 0, 0, 0);\
        }                                                                                \
        asm volatile("s_waitcnt lgkmcnt(0)" ::: "memory"); /* wave-wide ds_read drain */ \
        __builtin_amdgcn_sched_barrier(0);                                               \
        if (lane == 0)                                                                   \
            __atomic_fetch_add(&done[b], 1, __ATOMIC_RELEASE);                           \
    }

        for (int c = 0; c < 32; c += 2) {
            CONSUME(c, aE, aO)
            CONSUME(c + 1, aO, aE)
        }
#undef CONSUME

        // epilogue: dequant. C/D: col=lane&31, row=(g&3)+8*(g>>2)+4*(lane>>5)
        const int n = n0 + (lane & 31);
        const float wn = wscale[n];
        const float bn = bias[n];
        const int mb0 = (2 * wave) * 32 + 4 * (lane >> 5);
        const int mb1 = (2 * wave + 1) * 32 + 4 * (lane >> 5);
#pragma unroll
        for (int g = 0; g < 16; ++g) {
            const int dm = (g & 3) + 8 * (g >> 2);
            const int m0 = mb0 + dm;
            const int m1 = mb1 + dm;
            out[(size_t)m0 * N_ + n] = ((float)acc0[g] * scales[m0]) * wn + bn;
            out[(size_t)m1 * N_ + n] = ((float)acc1[g] * scales[m1]) * wn + bn;
        }
    }
}

extern "C" void kernel_launch(void* const* d_in, const int* in_sizes, int n_in,
                              void* d_out, int out_size, void* d_ws, size_t ws_size,
                              hipStream_t stream) {
    const float* x    = (const float*)d_in[0];
    const int*   qw   = (const int*)d_in[1];
    const float* wsc  = (const float*)d_in[2];
    const float* bias = (const float*)d_in[3];
    float* out = (float*)d_out;

    signed char* xqbuf  = (signed char*)d_ws;                      // 2 MB, tiled
    float*       scales = (float*)((char*)d_ws + (size_t)M_ * K_); // 1 KB

    awq_quant<<<M_, 256, 0, stream>>>(x, xqbuf, scales);
    awq_gemm_pc<<<N_ / 32, 512, 0, stream>>>(xqbuf, scales, qw, wsc, bias, out);
}

// Round 14
// 65.585 us; speedup vs baseline: 2.2232x; 1.0481x over previous
//
#include <hip/hip_runtime.h>

#define M_ 256
#define K_ 8192
#define N_ 8192

typedef int v4i __attribute__((ext_vector_type(4)));
typedef int v16i __attribute__((ext_vector_type(16)));

// ---------------- kernel 1: per-token int8 quantization (R6, proven) ------
// xq tiled layout (bijective byte map, 2 MB):
//   (m,k) -> addr = (mt<<18) + (chunk<<13) + (ks<<10) + (lane<<4) + b
__global__ __launch_bounds__(256) void awq_quant(const float* __restrict__ x,
                                                 signed char* __restrict__ xqt,
                                                 float* __restrict__ scales) {
    const int m = blockIdx.x;
    const int t = threadIdx.x;
    const float4* xrow = (const float4*)(x + (size_t)m * K_);
    float4 v[8];
    float mx = 0.0f;
#pragma unroll
    for (int j = 0; j < 8; ++j) {
        v[j] = xrow[j * 256 + t];
        mx = fmaxf(mx, fmaxf(fmaxf(fabsf(v[j].x), fabsf(v[j].y)),
                             fmaxf(fabsf(v[j].z), fabsf(v[j].w))));
    }
#pragma unroll
    for (int off = 32; off > 0; off >>= 1) mx = fmaxf(mx, __shfl_xor(mx, off, 64));
    __shared__ float red[4];
    if ((t & 63) == 0) red[t >> 6] = mx;
    __syncthreads();
    mx = fmaxf(fmaxf(red[0], red[1]), fmaxf(red[2], red[3]));
    const float scale = fmaxf(mx / 127.0f, 1e-8f);

    char* base = (char*)xqt + ((size_t)(m >> 5) << 18);
    const int ml = m & 31;
#pragma unroll
    for (int j = 0; j < 8; ++j) {
        const int q0 = (int)fminf(fmaxf(rintf(v[j].x / scale), -127.0f), 127.0f);
        const int q1 = (int)fminf(fmaxf(rintf(v[j].y / scale), -127.0f), 127.0f);
        const int q2 = (int)fminf(fmaxf(rintf(v[j].z / scale), -127.0f), 127.0f);
        const int q3 = (int)fminf(fmaxf(rintf(v[j].w / scale), -127.0f), 127.0f);
        const int packed = (q0 & 255) | ((q1 & 255) << 8) | ((q2 & 255) << 16) | ((q3 & 255) << 24);
        const int k0 = 4 * (j * 256 + t);
        const int addr = ((k0 >> 8) << 13) + (((k0 >> 5) & 7) << 10) +
                         ((ml + (((k0 >> 4) & 1) << 5)) << 4) + (k0 & 15);
        *(int*)(base + addr) = packed;
    }
    if (t == 0) scales[m] = scale;
}

// ---------------- kernel 2: int8 GEMM + dequant epilogue ----------------
// R6 structure (best: 63.9us) + T2 XOR-swizzled B-tile.
// OLD tile [32][272] had ds_read_b128 at bank 4*lane%32: lanes {l,l+8,l+16,
// l+24} same 4-bank group -> 4-way conflict, 8/32 banks active (~2000cy
// LDS serialization per phase, on the lgkm critical path). NEW: rows of
// 256B (16 slots of 16B), slot' = slot ^ (row&15):
//   addr(row, byte) = row*256 + ((byte>>4)^(row&15))*16 + (byte&15)
// reads: 16 slot-groups x 4 banks x 2 lanes = all 32 banks, 2-way (free);
// writes: 8 slots x 4 within x 2 lanes = free. Same involution both sides.
__global__ __launch_bounds__(512) void awq_gemm(const signed char* __restrict__ xqt,
                                                const float* __restrict__ scales,
                                                const int* __restrict__ qw,
                                                const float* __restrict__ wscale,
                                                const float* __restrict__ bias,
                                                float* __restrict__ out) {
    __shared__ __align__(16) char btile[2][32 * 256];   // 16 KB
    const int t = threadIdx.x;
    const int lane = t & 63;
    const int wave = t >> 6;
    const int n0 = blockIdx.x * 32;

    const int sa = t & 7;                  // n-group: cols n0 + 4*sa + j
    const int sr = t >> 3;                 // k-dword group (0..63)
    const int* qbase = qw + (size_t)(4 * sr) * N_ + n0 + 4 * sa;

    // tiled A base: wave's m-tile (256KB each), this lane's 16B slot
    const signed char* xqb = xqt + ((size_t)wave << 18) + lane * 16;

    // swizzled write offsets for the 4 staged dwords (j = row offset 0..3)
    int bwoj[4];
#pragma unroll
    for (int j = 0; j < 4; ++j) {
        const int row = 4 * sa + j;
        bwoj[j] = row * 256 + (((sr >> 2) ^ (row & 15)) << 4) + ((sr & 3) << 2);
    }
    // swizzled read offsets for the 8 B fragments (f = 0..7)
    const int brow = lane & 31;
    int brof[8];
#pragma unroll
    for (int f = 0; f < 8; ++f)
        brof[f] = brow * 256 + ((((lane >> 5) + 2 * f) ^ (brow & 15)) << 4);

    v16i acc = {};
    v4i aE[8], aO[8];
    int4 sA[4], sB[4];

    auto loadq = [&](int4* dst, int chunk) {
        const int4* q = (const int4*)(qbase + (size_t)chunk * 256 * N_);
        dst[0] = q[0];
        dst[1] = q[N_ / 4];
        dst[2] = q[2 * (N_ / 4)];
        dst[3] = q[3 * (N_ / 4)];
    };
    auto stage = [&](char* btn, const int4& w0, const int4& w1,
                     const int4& w2, const int4& w3) {
        const int* p0 = (const int*)&w0;
        const int* p1 = (const int*)&w1;
        const int* p2 = (const int*)&w2;
        const int* p3 = (const int*)&w3;
#pragma unroll
        for (int j = 0; j < 4; ++j) {
            const unsigned u = __builtin_amdgcn_perm((unsigned)p1[j], (unsigned)p0[j], 0x00000400u);
            const unsigned w = __builtin_amdgcn_perm((unsigned)p3[j], (unsigned)p2[j], 0x00000400u);
            const unsigned o = __builtin_amdgcn_perm(w, u, 0x05040100u);
            *(unsigned*)(btn + bwoj[j]) = o;
        }
    };

    // prologue: aE <- chunk0 frags; sA <- chunk0, sB <- chunk1; stage buf0
#pragma unroll
    for (int ks = 0; ks < 8; ++ks) aE[ks] = *(const v4i*)(xqb + ks * 1024);
    loadq(sA, 0);
    loadq(sB, 1);
    stage(&btile[0][0], sA[0], sA[1], sA[2], sA[3]);
    asm volatile("s_waitcnt lgkmcnt(0)" ::: "memory");
    __builtin_amdgcn_s_barrier();
    __builtin_amdgcn_sched_barrier(0);

    for (int sc = 0; sc < 32; sc += 2) {
        {   // even: compute chunk sc (buf0, aE); refill aO<-sc+1; loadq sA<-sc+2
            const int ra = (sc + 1 < 32) ? sc + 1 : 31;
#pragma unroll
            for (int ks = 0; ks < 8; ++ks)
                aO[ks] = *(const v4i*)(xqb + ra * 8192 + ks * 1024);
            loadq(sA, (sc + 2 < 32) ? sc + 2 : 31);
            __builtin_amdgcn_sched_barrier(0);
            const char* btc = &btile[0][0];
#pragma unroll
            for (int ks = 0; ks < 8; ++ks) {
                const v4i bf = *(const v4i*)(btc + brof[ks]);
                acc = __builtin_amdgcn_mfma_i32_32x32x32_i8(aE[ks], bf, acc, 0, 0, 0);
            }
            stage(&btile[1][0], sB[0], sB[1], sB[2], sB[3]);
            asm volatile("s_waitcnt lgkmcnt(0)" ::: "memory");
            __builtin_amdgcn_s_barrier();
            __builtin_amdgcn_sched_barrier(0);
        }
        {   // odd: compute chunk sc+1 (buf1, aO); refill aE<-sc+2; loadq sB<-sc+3
            const int ra = (sc + 2 < 32) ? sc + 2 : 31;
#pragma unroll
            for (int ks = 0; ks < 8; ++ks)
                aE[ks] = *(const v4i*)(xqb + ra * 8192 + ks * 1024);
            loadq(sB, (sc + 3 < 32) ? sc + 3 : 31);
            __builtin_amdgcn_sched_barrier(0);
            const char* btc = &btile[1][0];
#pragma unroll
            for (int ks = 0; ks < 8; ++ks) {
                const v4i bf = *(const v4i*)(btc + brof[ks]);
                acc = __builtin_amdgcn_mfma_i32_32x32x32_i8(aO[ks], bf, acc, 0, 0, 0);
            }
            stage(&btile[0][0], sA[0], sA[1], sA[2], sA[3]);
            asm volatile("s_waitcnt lgkmcnt(0)" ::: "memory");
            __builtin_amdgcn_s_barrier();
            __builtin_amdgcn_sched_barrier(0);
        }
    }

    // epilogue: dequant. C/D layout: col=lane&31, row=(g&3)+8*(g>>2)+4*(lane>>5)
    const int n = n0 + (lane & 31);
    const float wn = wscale[n];
    const float bn = bias[n];
    const int mb = wave * 32 + 4 * (lane >> 5);
#pragma unroll
    for (int g = 0; g < 16; ++g) {
        const int m = mb + (g & 3) + 8 * (g >> 2);
        out[(size_t)m * N_ + n] = ((float)acc[g] * scales[m]) * wn + bn;
    }
}

extern "C" void kernel_launch(void* const* d_in, const int* in_sizes, int n_in,
                              void* d_out, int out_size, void* d_ws, size_t ws_size,
                              hipStream_t stream) {
    const float* x    = (const float*)d_in[0];
    const int*   qw   = (const int*)d_in[1];
    const float* wsc  = (const float*)d_in[2];
    const float* bias = (const float*)d_in[3];
    float* out = (float*)d_out;

    signed char* xqbuf  = (signed char*)d_ws;                      // 2 MB, tiled
    float*       scales = (float*)((char*)d_ws + (size_t)M_ * K_); // 1 KB

    awq_quant<<<M_, 256, 0, stream>>>(x, xqbuf, scales);
    awq_gemm<<<N_ / 32, 512, 0, stream>>>(xqbuf, scales, qw, wsc, bias, out);
}